// Round 6
// baseline (27994.183 us; speedup 1.0000x reference)
//
#include <hip/hip_runtime.h>
#include <hip/hip_bf16.h>

// LSTMConvATTN — round 5: round-4 register math in a launch-proven geometry.
//   Round 4 failed because the 512-block cooperative launch was rejected
//   (absmax == empty-kernel signature -> lstm never ran). Round 5: 256 WGs x
//   1024 threads (the grid size rounds 1-3 launched fine), 16 sets x 16 WGs,
//   32 units/WG -> 64 weight floats/thread (16 float4), ~120 VGPR, no spill.
//   Coop-launch rc checked with regular-launch fallback (256 blocks @ 1/CU is
//   exactly co-resident anyway).

typedef unsigned short u16;
typedef unsigned int u32;

#define KV_ 320
#define GSET 16   // WGs per set
#define NSET 16
#define BSET 4
#define CNT_STRIDE 16  // u32s per counter (64B line)

__device__ __forceinline__ u16 f2bf(float f) {
  __hip_bfloat16 h = __float2bfloat16(f);
  return __builtin_bit_cast(u16, h);
}
__device__ __forceinline__ float blo(u32 u) { return __builtin_bit_cast(float, u << 16); }
__device__ __forceinline__ float bhi(u32 u) { return __builtin_bit_cast(float, u & 0xffff0000u); }

// coherent (L1/L2-bypass) bulk load: 16B per lane, waits inside
__device__ __forceinline__ float4 load_f4_coherent(const float* p) {
  float4 r;
  asm volatile("global_load_dwordx4 %0, %1, off sc0 sc1\n\t"
               "s_waitcnt vmcnt(0)"
               : "=v"(r) : "v"(p) : "memory");
  return r;
}
__device__ __forceinline__ void store_f_coherent(float* p, float v) {
  asm volatile("global_store_dword %0, %1, off sc0 sc1" :: "v"(p), "v"(v) : "memory");
}

// ---------------- prep ----------------
__global__ void veff_kernel(const float* __restrict__ Wv, float* __restrict__ Veff) {
  int i = blockIdx.x * blockDim.x + threadIdx.x;
  if (i < 262144) Veff[i] = Wv[i] + Wv[262144 + i];
}

// C[i][j] = (init?init[i][j]:0) + sum_o a[o*so + i*si] * Bsrc[o*512+j]
__global__ void eff_mat(const float* __restrict__ a, int so, int si,
                        const float* __restrict__ Bsrc, const float* __restrict__ initm,
                        float* __restrict__ C) {
  int i = blockIdx.x, j = threadIdx.x;
  float acc = initm ? initm[i * 512 + j] : 0.f;
  for (int o = 0; o < 512; ++o)
    acc = fmaf(a[o * so + i * si], Bsrc[o * 512 + j], acc);
  C[i * 512 + j] = acc;
}

// ---------------- LSTM (weight-resident, synced, 256 WGs x 1024 thr) --------
__global__ __launch_bounds__(1024, 4) void lstm_sync(
    const float* __restrict__ src,
    const float* __restrict__ W_ih, const float* __restrict__ W_hh,
    const float* __restrict__ b_ih, const float* __restrict__ b_hh,
    float* __restrict__ h_glob,   // [NSET][2][BSET][512]
    u32* __restrict__ cnt,        // [NSET][1024][CNT_STRIDE]
    float* __restrict__ enc_out,  // [64][KV_][512]
    float* __restrict__ h_n) {    // [64][512]
  const int tid = threadIdx.x;
  const int bid = blockIdx.x;
  // rounds-1-3 set mapping: 16 WGs of set s all have bid&7 == s&7 (XCD-local)
  const int xcd = bid & 7, jj = bid >> 3;
  const int s = xcd + 8 * (jj >> 4);
  const int wg = jj & 15;
  const int hb = wg * 32;          // hidden base: 32 units per WG
  const int bg0 = s * BSET;

  const int rg = tid >> 4;         // 0..63 : row group (2 rows each)
  const int ksub = tid & 15;       // 0..15 : k sub-range (32 k's each)
  const int sw3 = ksub & 7;        // read-side XOR swizzle key

  __shared__ __align__(16) float hl[4 * 512];     // [b][k] linear
  __shared__ __align__(16) float xl[2][4 * 64];   // double-buffered [b][k]
  __shared__ __align__(16) float gb[128 * 4];     // [r_local][b]

  // ---- resident weights: 2 rows x 32 k = 64 floats (16 float4) ----
  // row rl = rg*2+rr in 0..127; gate = rl>>5, unit = rl&31
  // slot (rr, j4) holds W_hh[grow, cols ksub*32 + (j4^sw3)*4 .. +3]
  float4 wreg[2][8];
  float4 wxreg[2];
#pragma unroll
  for (int rr = 0; rr < 2; ++rr) {
    const int rl = rg * 2 + rr;
    const int grow = ((rl >> 5) << 9) + hb + (rl & 31);
    const float* wrow = W_hh + (size_t)grow * 512 + (ksub << 5);
#pragma unroll
    for (int j4 = 0; j4 < 8; ++j4) {
      wreg[rr][j4] = *(const float4*)(wrow + ((j4 ^ sw3) << 2));
    }
    wxreg[rr] = *(const float4*)(W_ih + (size_t)grow * 64 + (ksub << 2));
  }

  // ---- update-thread state (tid<128: one (unit,batch) pair each) ----
  float bI = 0.f, bF = 0.f, bG = 0.f, bO = 0.f, cc = 0.f;
  const int ub = tid >> 2, bb = tid & 3;
  if (tid < 128) {
    const int r0 = hb + ub;
    bI = b_ih[r0] + b_hh[r0];
    bF = b_ih[512 + r0] + b_hh[512 + r0];
    bG = b_ih[1024 + r0] + b_hh[1024 + r0];
    bO = b_ih[1536 + r0] + b_hh[1536 + r0];
  }

  float* hg = h_glob + s * (2 * 2048);
  u32* cset = cnt + (size_t)s * 1024 * CNT_STRIDE;
  const float4* hl4 = (const float4*)hl;
  const int hbase = ksub << 3;

  // initial x load (t=0)
  if (tid < 256) {
    const int b = tid >> 6, k = tid & 63;
    xl[0][(b << 6) + k] = src[((size_t)(bg0 + b) * 1024 + 0) * 64 + k];
  }

  for (int t = 0; t < 1024; ++t) {
    // x(t+1) prefetch — issued before the poll so latency hides under the wait
    float xnext = 0.f;
    if (tid < 256 && t + 1 < 1024) {
      const int b = tid >> 6, k = tid & 63;
      xnext = src[((size_t)(bg0 + b) * 1024 + (t + 1)) * 64 + k];
    }
    // phase 1: wait for all WGs of the set to finish step t-1
    if (t > 0) {
      if (tid == 0) {
        while (__hip_atomic_load(&cset[(size_t)(t - 1) * CNT_STRIDE], __ATOMIC_ACQUIRE,
                                 __HIP_MEMORY_SCOPE_AGENT) < GSET) {
          __builtin_amdgcn_s_sleep(2);
        }
      }
      __syncthreads();  // B1
    }
    // phase 2: bulk h gather (coalesced, coherent) -> LDS (linear)
    if (tid < 512) {
      if (t == 0) {
        ((float4*)hl)[tid] = make_float4(0.f, 0.f, 0.f, 0.f);
      } else {
        const float* hgp = hg + (((t - 1) & 1) << 11) + (tid << 2);
        ((float4*)hl)[tid] = load_f4_coherent(hgp);
      }
    }
    __syncthreads();  // B2
    // phase 3: matvec (resident weights x LDS h), swizzled reads
    float acc[2][4];
#pragma unroll
    for (int rr = 0; rr < 2; ++rr)
#pragma unroll
      for (int b = 0; b < 4; ++b) acc[rr][b] = 0.f;
#pragma unroll
    for (int j4 = 0; j4 < 8; ++j4) {
      const int idx = hbase + (j4 ^ sw3);
      const float4 h0 = hl4[idx];
      const float4 h1 = hl4[128 + idx];
      const float4 h2 = hl4[256 + idx];
      const float4 h3 = hl4[384 + idx];
#pragma unroll
      for (int rr = 0; rr < 2; ++rr) {
        const float4 w = wreg[rr][j4];
        acc[rr][0] = fmaf(w.x, h0.x, fmaf(w.y, h0.y, fmaf(w.z, h0.z, fmaf(w.w, h0.w, acc[rr][0]))));
        acc[rr][1] = fmaf(w.x, h1.x, fmaf(w.y, h1.y, fmaf(w.z, h1.z, fmaf(w.w, h1.w, acc[rr][1]))));
        acc[rr][2] = fmaf(w.x, h2.x, fmaf(w.y, h2.y, fmaf(w.z, h2.z, fmaf(w.w, h2.w, acc[rr][2]))));
        acc[rr][3] = fmaf(w.x, h3.x, fmaf(w.y, h3.y, fmaf(w.z, h3.z, fmaf(w.w, h3.w, acc[rr][3]))));
      }
    }
    {
      const float4* xl4p = (const float4*)xl[t & 1];
      const float4 x0 = xl4p[ksub];
      const float4 x1 = xl4p[16 + ksub];
      const float4 x2 = xl4p[32 + ksub];
      const float4 x3 = xl4p[48 + ksub];
#pragma unroll
      for (int rr = 0; rr < 2; ++rr) {
        const float4 w = wxreg[rr];
        acc[rr][0] = fmaf(w.x, x0.x, fmaf(w.y, x0.y, fmaf(w.z, x0.z, fmaf(w.w, x0.w, acc[rr][0]))));
        acc[rr][1] = fmaf(w.x, x1.x, fmaf(w.y, x1.y, fmaf(w.z, x1.z, fmaf(w.w, x1.w, acc[rr][1]))));
        acc[rr][2] = fmaf(w.x, x2.x, fmaf(w.y, x2.y, fmaf(w.z, x2.z, fmaf(w.w, x2.w, acc[rr][2]))));
        acc[rr][3] = fmaf(w.x, x3.x, fmaf(w.y, x3.y, fmaf(w.z, x3.z, fmaf(w.w, x3.w, acc[rr][3]))));
      }
    }
    // reduce over 16 k-lanes (within-wave, width 16)
#pragma unroll
    for (int off = 1; off < 16; off <<= 1) {
#pragma unroll
      for (int rr = 0; rr < 2; ++rr) {
#pragma unroll
        for (int b = 0; b < 4; ++b)
          acc[rr][b] += __shfl_xor(acc[rr][b], off, 16);
      }
    }
    if (ksub == 0) {
#pragma unroll
      for (int rr = 0; rr < 2; ++rr)
        ((float4*)gb)[rg * 2 + rr] = make_float4(acc[rr][0], acc[rr][1], acc[rr][2], acc[rr][3]);
    }
    __syncthreads();  // B3
    // phase 4a: stash prefetched x
    if (tid < 256 && t + 1 < 1024) xl[(t + 1) & 1][tid] = xnext;
    // phase 4b: gate update + h publication (gb[rl][b], rl = gate*32 + unit)
    if (tid < 128) {
      const float gi = gb[(ub) * 4 + bb] + bI;
      const float gf = gb[(32 + ub) * 4 + bb] + bF;
      const float gg = gb[(64 + ub) * 4 + bb] + bG;
      const float go = gb[(96 + ub) * 4 + bb] + bO;
      const float iv = 1.f / (1.f + expf(-gi));
      const float fv = 1.f / (1.f + expf(-gf));
      const float gv = tanhf(gg);
      const float ov = 1.f / (1.f + expf(-go));
      cc = fv * cc + iv * gv;
      const float hv = ov * tanhf(cc);
      store_f_coherent(&hg[((t & 1) << 11) + (bb << 9) + hb + ub], hv);
      if (t < KV_) enc_out[((size_t)(bg0 + bb) * KV_ + t) * 512 + hb + ub] = hv;
      if (t == 1023) h_n[(size_t)(bg0 + bb) * 512 + hb + ub] = hv;
    }
    asm volatile("s_waitcnt vmcnt(0)" ::: "memory");  // drain h stores (every wave)
    __syncthreads();  // B4
    // phase 5: arrive
    if (t < 1023 && tid == 0) {
      __hip_atomic_fetch_add(&cset[(size_t)t * CNT_STRIDE], 1u, __ATOMIC_RELEASE,
                             __HIP_MEMORY_SCOPE_AGENT);
    }
  }
}

// ---------------- panel GEMM (fp32 in, bf16 out) ----------------
__global__ __launch_bounds__(256) void gemm_panel(
    const float* __restrict__ A, int M, int nseg, int shifted,
    const float* __restrict__ Bm, const float* __restrict__ bias,
    u16* __restrict__ C) {
  __shared__ float As[16][72];
  __shared__ float Bs[16][64];
  const int tid = threadIdx.x;
  const int nx = blockIdx.x, my = blockIdx.y;
  const int tx = tid & 15, ty = tid >> 4;
  const int m0 = ty * 4, n0 = tx * 4;
  const int lr = tid >> 2, lc = (tid & 3) * 4;
  const int kr = tid >> 4, nc = (tid & 15) * 4;
  float acc[4][4] = {};
  const int KK = nseg * 512;
  const int rA = my * 64 + lr;
  const int tloc = rA % KV_;
  for (int kk = 0; kk < KK; kk += 16) {
    const int seg = kk >> 9, k0 = kk & 511;
    float4 av = make_float4(0.f, 0.f, 0.f, 0.f);
    if (rA < M) {
      int arow = rA, valid = 1;
      if (shifted) { arow = rA + seg - 2; valid = (tloc + seg - 2) >= 0; }
      if (valid) av = *(const float4*)&A[(size_t)arow * 512 + k0 + lc];
    }
    As[lc + 0][lr] = av.x; As[lc + 1][lr] = av.y;
    As[lc + 2][lr] = av.z; As[lc + 3][lr] = av.w;
    *(float4*)&Bs[kr][nc] = *(const float4*)&Bm[(size_t)(kk + kr) * 512 + nx * 64 + nc];
    __syncthreads();
#pragma unroll
    for (int k = 0; k < 16; ++k) {
      float4 A4 = *(const float4*)&As[k][m0];
      float4 B4 = *(const float4*)&Bs[k][n0];
      float ar[4] = {A4.x, A4.y, A4.z, A4.w};
      float br[4] = {B4.x, B4.y, B4.z, B4.w};
#pragma unroll
      for (int ii = 0; ii < 4; ++ii)
#pragma unroll
        for (int jj = 0; jj < 4; ++jj)
          acc[ii][jj] = fmaf(ar[ii], br[jj], acc[ii][jj]);
    }
    __syncthreads();
  }
#pragma unroll
  for (int ii = 0; ii < 4; ++ii) {
    int r = my * 64 + m0 + ii;
    if (r < M) {
#pragma unroll
      for (int jj = 0; jj < 4; ++jj) {
        int col = nx * 64 + n0 + jj;
        float v = acc[ii][jj] + (bias ? bias[col] : 0.f);
        C[(size_t)r * 512 + col] = f2bf(v);
      }
    }
  }
}

// ---------------- attention + head ----------------
__global__ __launch_bounds__(256) void attn_final(
    const u16* __restrict__ Qp, const u16* __restrict__ Kp, const u16* __restrict__ Vp,
    const float* __restrict__ h_n, const float* __restrict__ Wfc,
    const float* __restrict__ catW, const float* __restrict__ catb,
    const float* __restrict__ outW, float* __restrict__ out) {
  const int b = blockIdx.x, tid = threadIdx.x;
  __shared__ float sc[8 * KV_];
  __shared__ float ctx[512];
  __shared__ float av[512];
  __shared__ float ha[64];
  __shared__ uint4 qs[64];
  if (tid < 64) qs[tid] = ((const uint4*)(Qp + (size_t)b * 512))[tid];
  __syncthreads();
  for (int idx = tid; idx < 8 * KV_; idx += 256) {
    int h = idx / KV_, t = idx % KV_;
    const uint4* kr4 = (const uint4*)(Kp + ((size_t)(b * KV_ + t)) * 512 + h * 64);
    float s = 0.f;
#pragma unroll
    for (int u = 0; u < 8; ++u) {
      uint4 kv = kr4[u]; uint4 qv = qs[h * 8 + u];
      s += blo(kv.x) * blo(qv.x) + bhi(kv.x) * bhi(qv.x)
         + blo(kv.y) * blo(qv.y) + bhi(kv.y) * bhi(qv.y)
         + blo(kv.z) * blo(qv.z) + bhi(kv.z) * bhi(qv.z)
         + blo(kv.w) * blo(qv.w) + bhi(kv.w) * bhi(qv.w);
    }
    sc[h * KV_ + t] = s * 0.125f;
  }
  __syncthreads();
  {
    int h = tid >> 5, l = tid & 31;
    float m = -1e30f;
    for (int t = l; t < KV_; t += 32) m = fmaxf(m, sc[h * KV_ + t]);
    for (int o = 16; o; o >>= 1) m = fmaxf(m, __shfl_xor(m, o, 32));
    float sum = 0.f;
    for (int t = l; t < KV_; t += 32) { float e = expf(sc[h * KV_ + t] - m); sc[h * KV_ + t] = e; sum += e; }
    for (int o = 16; o; o >>= 1) sum += __shfl_xor(sum, o, 32);
    float inv = 1.f / sum;
    for (int t = l; t < KV_; t += 32) sc[h * KV_ + t] *= inv;
  }
  __syncthreads();
  for (int j = tid; j < 512; j += 256) {
    int h = j >> 6, d = j & 63;
    const u16* vp = Vp + (size_t)(b * KV_) * 512 + h * 64 + d;
    float a = 0.f;
    for (int t = 0; t < KV_; ++t)
      a = fmaf(sc[h * KV_ + t], blo((u32)vp[(size_t)t * 512]), a);
    ctx[j] = a;
  }
  __syncthreads();
  for (int j = tid; j < 512; j += 256) {
    float a = 0.f;
    for (int i = 0; i < 512; ++i) a = fmaf(ctx[i], Wfc[(size_t)i * 512 + j], a);
    av[j] = a;
  }
  __syncthreads();
  if (tid < 64) {
    float a = catb[tid];
    const float* hb = h_n + (size_t)b * 512;
    for (int i = 0; i < 512; ++i) a = fmaf(hb[i], catW[i * 64 + tid], a);
    for (int i = 0; i < 512; ++i) a = fmaf(av[i], catW[(512 + i) * 64 + tid], a);
    ha[tid] = a;
  }
  __syncthreads();
  if (tid < 64) {
    float v = ha[tid] * outW[tid];
    for (int o = 32; o; o >>= 1) v += __shfl_xor(v, o, 64);
    if (tid == 0) out[b] = v;
  }
}

extern "C" void kernel_launch(void* const* d_in, const int* in_sizes, int n_in,
                              void* d_out, int out_size, void* d_ws, size_t ws_size,
                              hipStream_t stream) {
  const float* src   = (const float*)d_in[0];
  const float* W_ih  = (const float*)d_in[2];
  const float* W_hh  = (const float*)d_in[3];
  const float* b_ih  = (const float*)d_in[4];
  const float* b_hh  = (const float*)d_in[5];
  const float* convw = (const float*)d_in[6];
  const float* convb = (const float*)d_in[7];
  const float* Wq    = (const float*)d_in[8];
  const float* Wk    = (const float*)d_in[9];
  const float* Wv    = (const float*)d_in[10];
  const float* Wfc   = (const float*)d_in[11];
  const float* catW  = (const float*)d_in[12];
  const float* catb  = (const float*)d_in[13];
  const float* outW  = (const float*)d_in[14];
  float* out = (float*)d_out;

  char* w = (char*)d_ws;
  float* Beff  = (float*)w;  w += (size_t)3 * 512 * 512 * 4;
  float* Qeff  = (float*)w;  w += (size_t)512 * 512 * 4;
  float* Veff  = (float*)w;  w += (size_t)512 * 512 * 4;
  float* kb    = (float*)w;  w += 512 * 4;
  float* qb    = (float*)w;  w += 512 * 4;
  float* h_n   = (float*)w;  w += (size_t)64 * 512 * 4;
  float* enc   = (float*)w;  w += (size_t)64 * KV_ * 512 * 4;
  u16*   Kp    = (u16*)w;    w += (size_t)64 * KV_ * 512 * 2;
  u16*   Vp    = (u16*)w;    w += (size_t)64 * KV_ * 512 * 2;
  u16*   Qp    = (u16*)w;    w += (size_t)64 * 512 * 2;
  float* h_glob = (float*)w; w += (size_t)NSET * 2 * 2048 * 4;
  u32*   cnt   = (u32*)w;    w += (size_t)NSET * 1024 * CNT_STRIDE * 4;

  veff_kernel<<<1024, 256, 0, stream>>>(Wv, Veff);
  eff_mat<<<512, 512, 0, stream>>>(convw + 0, 1536, 3, Wk + 262144, nullptr, Beff);
  eff_mat<<<512, 512, 0, stream>>>(convw + 1, 1536, 3, Wk + 262144, nullptr, Beff + 262144);
  eff_mat<<<512, 512, 0, stream>>>(convw + 2, 1536, 3, Wk + 262144, Wk, Beff + 524288);
  eff_mat<<<512, 512, 0, stream>>>(convw + 2, 1536, 3, Wq + 262144, Wq, Qeff);
  eff_mat<<<1, 512, 0, stream>>>(convb, 1, 0, Wk + 262144, nullptr, kb);
  eff_mat<<<1, 512, 0, stream>>>(convb, 1, 0, Wq + 262144, nullptr, qb);

  hipMemsetAsync((void*)cnt, 0, (size_t)NSET * 1024 * CNT_STRIDE * 4, stream);
  {
    const float* a_src = src; const float* a_wih = W_ih; const float* a_whh = W_hh;
    const float* a_bih = b_ih; const float* a_bhh = b_hh;
    float* a_hg = h_glob; u32* a_cnt = cnt; float* a_enc = enc; float* a_hn = h_n;
    void* args[] = {(void*)&a_src, (void*)&a_wih, (void*)&a_whh, (void*)&a_bih,
                    (void*)&a_bhh, (void*)&a_hg, (void*)&a_cnt, (void*)&a_enc, (void*)&a_hn};
    hipError_t rc = hipLaunchCooperativeKernel(lstm_sync, dim3(256), dim3(1024), args, 0, stream);
    if (rc != hipSuccess) {
      // fallback: regular launch; 256 blocks at 1 block/CU occupancy are
      // co-resident on the 256-CU device (grid == CU count).
      lstm_sync<<<256, 1024, 0, stream>>>(src, W_ih, W_hh, b_ih, b_hh,
                                          h_glob, cnt, enc, h_n);
    }
  }

  gemm_panel<<<dim3(8, KV_), 256, 0, stream>>>(enc, 64 * KV_, 3, 1, Beff, kb, Kp);
  gemm_panel<<<dim3(8, KV_), 256, 0, stream>>>(enc, 64 * KV_, 1, 0, Veff, nullptr, Vp);
  gemm_panel<<<dim3(8, 1), 256, 0, stream>>>(h_n, 64, 1, 0, Qeff, qb, Qp);
  attn_final<<<64, 256, 0, stream>>>(Qp, Kp, Vp, h_n, Wfc, catW, catb, outW, out);
}

// Round 7
// 13226.472 us; speedup vs baseline: 2.1165x; 2.1165x over previous
//
#include <hip/hip_runtime.h>
#include <hip/hip_bf16.h>

// LSTMConvATTN — round 6: 256-thread WGs to unlock the 256-VGPR budget.
//   Empirical allocator rule from rounds 1-5: VGPR cap = 65536/block_size
//   (512thr->128, 1024thr->64) -> every "resident" design spilled. 256thr
//   blocks should get 256 (m97: 164 VGPR @ 256thr). New geometry:
//   8 sets x 32 WGs x 256 thr; set=XCD heuristic; 8 batches/set; WG owns 16
//   units (64 gate rows); thread = 4 rows x 32 k = 128 weight floats (~220
//   VGPR total). 4 rows/thread also halves LDS h-read amplification.
//   h gather: 4 loads in ONE asm block, single waitcnt, sched_barrier fence.

typedef unsigned short u16;
typedef unsigned int u32;

#define KV_ 320
#define GSET 32   // WGs per set
#define NSET 8
#define BSET 8
#define CNT_STRIDE 16  // u32s per counter (64B line)

__device__ __forceinline__ u16 f2bf(float f) {
  __hip_bfloat16 h = __float2bfloat16(f);
  return __builtin_bit_cast(u16, h);
}
__device__ __forceinline__ float blo(u32 u) { return __builtin_bit_cast(float, u << 16); }
__device__ __forceinline__ float bhi(u32 u) { return __builtin_bit_cast(float, u & 0xffff0000u); }

__device__ __forceinline__ void store_f_coherent(float* p, float v) {
  asm volatile("global_store_dword %0, %1, off sc0 sc1" :: "v"(p), "v"(v) : "memory");
}

// ---------------- prep ----------------
__global__ void veff_kernel(const float* __restrict__ Wv, float* __restrict__ Veff) {
  int i = blockIdx.x * blockDim.x + threadIdx.x;
  if (i < 262144) Veff[i] = Wv[i] + Wv[262144 + i];
}

// C[i][j] = (init?init[i][j]:0) + sum_o a[o*so + i*si] * Bsrc[o*512+j]
__global__ void eff_mat(const float* __restrict__ a, int so, int si,
                        const float* __restrict__ Bsrc, const float* __restrict__ initm,
                        float* __restrict__ C) {
  int i = blockIdx.x, j = threadIdx.x;
  float acc = initm ? initm[i * 512 + j] : 0.f;
  for (int o = 0; o < 512; ++o)
    acc = fmaf(a[o * so + i * si], Bsrc[o * 512 + j], acc);
  C[i * 512 + j] = acc;
}

// ---------------- LSTM (weight-resident, synced, 256 WGs x 256 thr) --------
__global__ __launch_bounds__(256) void lstm_sync(
    const float* __restrict__ src,
    const float* __restrict__ W_ih, const float* __restrict__ W_hh,
    const float* __restrict__ b_ih, const float* __restrict__ b_hh,
    float* __restrict__ h_glob,   // [NSET][2][BSET][512]
    u32* __restrict__ cnt,        // [NSET][1024][CNT_STRIDE]
    float* __restrict__ enc_out,  // [64][KV_][512]
    float* __restrict__ h_n) {    // [64][512]
  const int tid = threadIdx.x;
  const int bid = blockIdx.x;
  const int s = bid & 7;           // set = XCD heuristic (correctness XCD-agnostic)
  const int wg = bid >> 3;         // 0..31
  const int hb = wg * 16;          // 16 hidden units per WG
  const int bg0 = s * BSET;

  const int rg = tid >> 4;         // 0..15 : row group (4 rows each)
  const int ksub = tid & 15;       // 0..15 : k sub-range (32 k's each)
  const int sw3 = ksub & 7;        // read-side XOR swizzle key

  __shared__ __align__(16) float hl[8 * 512];     // [b][k] linear (16 KB)
  __shared__ __align__(16) float xl[2][8 * 64];   // double-buffered [b][k] (4 KB)
  __shared__ __align__(16) float gb[64 * 8];      // [r_local][b] (2 KB)

  // ---- resident weights: 4 rows x 32 k = 128 floats (32 float4) ----
  // row rl = rg*4+rr in 0..63; gate = rl>>4, unit_local = rl&15
  // slot (rr, j4) holds W_hh[grow, cols ksub*32 + (j4^sw3)*4 .. +3]
  float4 wreg[4][8];
  float4 wxreg[4];
#pragma unroll
  for (int rr = 0; rr < 4; ++rr) {
    const int rl = rg * 4 + rr;
    const int grow = ((rl >> 4) << 9) + hb + (rl & 15);
    const float* wrow = W_hh + (size_t)grow * 512 + (ksub << 5);
#pragma unroll
    for (int j4 = 0; j4 < 8; ++j4) {
      wreg[rr][j4] = *(const float4*)(wrow + ((j4 ^ sw3) << 2));
    }
    wxreg[rr] = *(const float4*)(W_ih + (size_t)grow * 64 + (ksub << 2));
  }

  // ---- update-thread state (tid<128: one (unit,batch) pair each) ----
  float bI = 0.f, bF = 0.f, bG = 0.f, bO = 0.f, cc = 0.f;
  const int ul = tid >> 3, bb = tid & 7;
  if (tid < 128) {
    const int r0 = hb + ul;
    bI = b_ih[r0] + b_hh[r0];
    bF = b_ih[512 + r0] + b_hh[512 + r0];
    bG = b_ih[1024 + r0] + b_hh[1024 + r0];
    bO = b_ih[1536 + r0] + b_hh[1536 + r0];
  }

  float* hg = h_glob + s * (2 * BSET * 512);
  u32* cset = cnt + (size_t)s * 1024 * CNT_STRIDE;
  const float4* hl4 = (const float4*)hl;
  const int hbase = ksub << 3;

  // initial x load (t=0): 512 floats, 2 per thread
  {
    xl[0][tid] = src[((size_t)(bg0 + (tid >> 6)) * 1024 + 0) * 64 + (tid & 63)];
    const int i2 = tid + 256;
    xl[0][i2] = src[((size_t)(bg0 + (i2 >> 6)) * 1024 + 0) * 64 + (i2 & 63)];
  }

  for (int t = 0; t < 1024; ++t) {
    // x(t+1) prefetch — issued before the poll so latency hides under the wait
    float xn0 = 0.f, xn1 = 0.f;
    if (t + 1 < 1024) {
      xn0 = src[((size_t)(bg0 + (tid >> 6)) * 1024 + (t + 1)) * 64 + (tid & 63)];
      const int i2 = tid + 256;
      xn1 = src[((size_t)(bg0 + (i2 >> 6)) * 1024 + (t + 1)) * 64 + (i2 & 63)];
    }
    // phase 1: wait for all WGs of the set to finish step t-1
    if (t > 0) {
      if (tid == 0) {
        while (__hip_atomic_load(&cset[(size_t)(t - 1) * CNT_STRIDE], __ATOMIC_ACQUIRE,
                                 __HIP_MEMORY_SCOPE_AGENT) < GSET) {
          __builtin_amdgcn_s_sleep(2);
        }
      }
      __syncthreads();  // B1
    }
    // phase 2: bulk h gather (coalesced, coherent): 4096 floats, 4 float4/thread
    if (t == 0) {
      const float4 z = make_float4(0.f, 0.f, 0.f, 0.f);
      ((float4*)hl)[tid] = z;
      ((float4*)hl)[tid + 256] = z;
      ((float4*)hl)[tid + 512] = z;
      ((float4*)hl)[tid + 768] = z;
    } else {
      const float* hp = hg + (((t - 1) & 1) * (BSET * 512));
      float4 r0, r1, r2, r3;
      const float* p0 = hp + (tid << 2);
      const float* p1 = hp + ((tid + 256) << 2);
      const float* p2 = hp + ((tid + 512) << 2);
      const float* p3 = hp + ((tid + 768) << 2);
      asm volatile(
          "global_load_dwordx4 %0, %4, off sc0 sc1\n\t"
          "global_load_dwordx4 %1, %5, off sc0 sc1\n\t"
          "global_load_dwordx4 %2, %6, off sc0 sc1\n\t"
          "global_load_dwordx4 %3, %7, off sc0 sc1\n\t"
          "s_waitcnt vmcnt(0)"
          : "=&v"(r0), "=&v"(r1), "=&v"(r2), "=&v"(r3)
          : "v"(p0), "v"(p1), "v"(p2), "v"(p3)
          : "memory");
      __builtin_amdgcn_sched_barrier(0);  // keep LDS writes after the waitcnt
      ((float4*)hl)[tid] = r0;
      ((float4*)hl)[tid + 256] = r1;
      ((float4*)hl)[tid + 512] = r2;
      ((float4*)hl)[tid + 768] = r3;
    }
    __syncthreads();  // B2
    // phase 3: matvec (resident weights x LDS h), swizzled reads
    float acc[4][8];
#pragma unroll
    for (int rr = 0; rr < 4; ++rr)
#pragma unroll
      for (int b = 0; b < 8; ++b) acc[rr][b] = 0.f;
#pragma unroll
    for (int j4 = 0; j4 < 8; ++j4) {
      const int idx = hbase + (j4 ^ sw3);
      float4 hv[8];
#pragma unroll
      for (int b = 0; b < 8; ++b) hv[b] = hl4[b * 128 + idx];
#pragma unroll
      for (int rr = 0; rr < 4; ++rr) {
        const float4 w = wreg[rr][j4];
#pragma unroll
        for (int b = 0; b < 8; ++b) {
          acc[rr][b] = fmaf(w.x, hv[b].x, fmaf(w.y, hv[b].y,
                       fmaf(w.z, hv[b].z, fmaf(w.w, hv[b].w, acc[rr][b]))));
        }
      }
    }
    {
      const float4* xl4p = (const float4*)xl[t & 1];
      float4 xv[8];
#pragma unroll
      for (int b = 0; b < 8; ++b) xv[b] = xl4p[b * 16 + ksub];
#pragma unroll
      for (int rr = 0; rr < 4; ++rr) {
        const float4 w = wxreg[rr];
#pragma unroll
        for (int b = 0; b < 8; ++b) {
          acc[rr][b] = fmaf(w.x, xv[b].x, fmaf(w.y, xv[b].y,
                       fmaf(w.z, xv[b].z, fmaf(w.w, xv[b].w, acc[rr][b]))));
        }
      }
    }
    // reduce over 16 k-lanes (within-wave, width 16)
#pragma unroll
    for (int off = 1; off < 16; off <<= 1) {
#pragma unroll
      for (int rr = 0; rr < 4; ++rr) {
#pragma unroll
        for (int b = 0; b < 8; ++b)
          acc[rr][b] += __shfl_xor(acc[rr][b], off, 16);
      }
    }
    if (ksub == 0) {
#pragma unroll
      for (int rr = 0; rr < 4; ++rr) {
        const int rl = rg * 4 + rr;
        ((float4*)gb)[rl * 2 + 0] = make_float4(acc[rr][0], acc[rr][1], acc[rr][2], acc[rr][3]);
        ((float4*)gb)[rl * 2 + 1] = make_float4(acc[rr][4], acc[rr][5], acc[rr][6], acc[rr][7]);
      }
    }
    __syncthreads();  // B3
    // phase 4a: stash prefetched x
    if (t + 1 < 1024) {
      xl[(t + 1) & 1][tid] = xn0;
      xl[(t + 1) & 1][tid + 256] = xn1;
    }
    // phase 4b: gate update + h publication (gb[rl][b], rl = gate*16 + unit)
    if (tid < 128) {
      const float gi = gb[(ul) * 8 + bb] + bI;
      const float gf = gb[(16 + ul) * 8 + bb] + bF;
      const float gg = gb[(32 + ul) * 8 + bb] + bG;
      const float go = gb[(48 + ul) * 8 + bb] + bO;
      const float iv = 1.f / (1.f + expf(-gi));
      const float fv = 1.f / (1.f + expf(-gf));
      const float gv = tanhf(gg);
      const float ov = 1.f / (1.f + expf(-go));
      cc = fv * cc + iv * gv;
      const float hv = ov * tanhf(cc);
      store_f_coherent(&hg[(t & 1) * (BSET * 512) + (bb << 9) + hb + ul], hv);
      if (t < KV_) enc_out[((size_t)(bg0 + bb) * KV_ + t) * 512 + hb + ul] = hv;
      if (t == 1023) h_n[(size_t)(bg0 + bb) * 512 + hb + ul] = hv;
    }
    asm volatile("s_waitcnt vmcnt(0)" ::: "memory");  // drain h stores (every wave)
    __syncthreads();  // B4
    // phase 5: arrive
    if (t < 1023 && tid == 0) {
      __hip_atomic_fetch_add(&cset[(size_t)t * CNT_STRIDE], 1u, __ATOMIC_RELEASE,
                             __HIP_MEMORY_SCOPE_AGENT);
    }
  }
}

// ---------------- panel GEMM (fp32 in, bf16 out) ----------------
__global__ __launch_bounds__(256) void gemm_panel(
    const float* __restrict__ A, int M, int nseg, int shifted,
    const float* __restrict__ Bm, const float* __restrict__ bias,
    u16* __restrict__ C) {
  __shared__ float As[16][72];
  __shared__ float Bs[16][64];
  const int tid = threadIdx.x;
  const int nx = blockIdx.x, my = blockIdx.y;
  const int tx = tid & 15, ty = tid >> 4;
  const int m0 = ty * 4, n0 = tx * 4;
  const int lr = tid >> 2, lc = (tid & 3) * 4;
  const int kr = tid >> 4, nc = (tid & 15) * 4;
  float acc[4][4] = {};
  const int KK = nseg * 512;
  const int rA = my * 64 + lr;
  const int tloc = rA % KV_;
  for (int kk = 0; kk < KK; kk += 16) {
    const int seg = kk >> 9, k0 = kk & 511;
    float4 av = make_float4(0.f, 0.f, 0.f, 0.f);
    if (rA < M) {
      int arow = rA, valid = 1;
      if (shifted) { arow = rA + seg - 2; valid = (tloc + seg - 2) >= 0; }
      if (valid) av = *(const float4*)&A[(size_t)arow * 512 + k0 + lc];
    }
    As[lc + 0][lr] = av.x; As[lc + 1][lr] = av.y;
    As[lc + 2][lr] = av.z; As[lc + 3][lr] = av.w;
    *(float4*)&Bs[kr][nc] = *(const float4*)&Bm[(size_t)(kk + kr) * 512 + nx * 64 + nc];
    __syncthreads();
#pragma unroll
    for (int k = 0; k < 16; ++k) {
      float4 A4 = *(const float4*)&As[k][m0];
      float4 B4 = *(const float4*)&Bs[k][n0];
      float ar[4] = {A4.x, A4.y, A4.z, A4.w};
      float br[4] = {B4.x, B4.y, B4.z, B4.w};
#pragma unroll
      for (int ii = 0; ii < 4; ++ii)
#pragma unroll
        for (int jj = 0; jj < 4; ++jj)
          acc[ii][jj] = fmaf(ar[ii], br[jj], acc[ii][jj]);
    }
    __syncthreads();
  }
#pragma unroll
  for (int ii = 0; ii < 4; ++ii) {
    int r = my * 64 + m0 + ii;
    if (r < M) {
#pragma unroll
      for (int jj = 0; jj < 4; ++jj) {
        int col = nx * 64 + n0 + jj;
        float v = acc[ii][jj] + (bias ? bias[col] : 0.f);
        C[(size_t)r * 512 + col] = f2bf(v);
      }
    }
  }
}

// ---------------- attention + head ----------------
__global__ __launch_bounds__(256) void attn_final(
    const u16* __restrict__ Qp, const u16* __restrict__ Kp, const u16* __restrict__ Vp,
    const float* __restrict__ h_n, const float* __restrict__ Wfc,
    const float* __restrict__ catW, const float* __restrict__ catb,
    const float* __restrict__ outW, float* __restrict__ out) {
  const int b = blockIdx.x, tid = threadIdx.x;
  __shared__ float sc[8 * KV_];
  __shared__ float ctx[512];
  __shared__ float av[512];
  __shared__ float ha[64];
  __shared__ uint4 qs[64];
  if (tid < 64) qs[tid] = ((const uint4*)(Qp + (size_t)b * 512))[tid];
  __syncthreads();
  for (int idx = tid; idx < 8 * KV_; idx += 256) {
    int h = idx / KV_, t = idx % KV_;
    const uint4* kr4 = (const uint4*)(Kp + ((size_t)(b * KV_ + t)) * 512 + h * 64);
    float s = 0.f;
#pragma unroll
    for (int u = 0; u < 8; ++u) {
      uint4 kv = kr4[u]; uint4 qv = qs[h * 8 + u];
      s += blo(kv.x) * blo(qv.x) + bhi(kv.x) * bhi(qv.x)
         + blo(kv.y) * blo(qv.y) + bhi(kv.y) * bhi(qv.y)
         + blo(kv.z) * blo(qv.z) + bhi(kv.z) * bhi(qv.z)
         + blo(kv.w) * blo(qv.w) + bhi(kv.w) * bhi(qv.w);
    }
    sc[h * KV_ + t] = s * 0.125f;
  }
  __syncthreads();
  {
    int h = tid >> 5, l = tid & 31;
    float m = -1e30f;
    for (int t = l; t < KV_; t += 32) m = fmaxf(m, sc[h * KV_ + t]);
    for (int o = 16; o; o >>= 1) m = fmaxf(m, __shfl_xor(m, o, 32));
    float sum = 0.f;
    for (int t = l; t < KV_; t += 32) { float e = expf(sc[h * KV_ + t] - m); sc[h * KV_ + t] = e; sum += e; }
    for (int o = 16; o; o >>= 1) sum += __shfl_xor(sum, o, 32);
    float inv = 1.f / sum;
    for (int t = l; t < KV_; t += 32) sc[h * KV_ + t] *= inv;
  }
  __syncthreads();
  for (int j = tid; j < 512; j += 256) {
    int h = j >> 6, d = j & 63;
    const u16* vp = Vp + (size_t)(b * KV_) * 512 + h * 64 + d;
    float a = 0.f;
    for (int t = 0; t < KV_; ++t)
      a = fmaf(sc[h * KV_ + t], blo((u32)vp[(size_t)t * 512]), a);
    ctx[j] = a;
  }
  __syncthreads();
  for (int j = tid; j < 512; j += 256) {
    float a = 0.f;
    for (int i = 0; i < 512; ++i) a = fmaf(ctx[i], Wfc[(size_t)i * 512 + j], a);
    av[j] = a;
  }
  __syncthreads();
  if (tid < 64) {
    float a = catb[tid];
    const float* hb = h_n + (size_t)b * 512;
    for (int i = 0; i < 512; ++i) a = fmaf(hb[i], catW[i * 64 + tid], a);
    for (int i = 0; i < 512; ++i) a = fmaf(av[i], catW[(512 + i) * 64 + tid], a);
    ha[tid] = a;
  }
  __syncthreads();
  if (tid < 64) {
    float v = ha[tid] * outW[tid];
    for (int o = 32; o; o >>= 1) v += __shfl_xor(v, o, 64);
    if (tid == 0) out[b] = v;
  }
}

extern "C" void kernel_launch(void* const* d_in, const int* in_sizes, int n_in,
                              void* d_out, int out_size, void* d_ws, size_t ws_size,
                              hipStream_t stream) {
  const float* src   = (const float*)d_in[0];
  const float* W_ih  = (const float*)d_in[2];
  const float* W_hh  = (const float*)d_in[3];
  const float* b_ih  = (const float*)d_in[4];
  const float* b_hh  = (const float*)d_in[5];
  const float* convw = (const float*)d_in[6];
  const float* convb = (const float*)d_in[7];
  const float* Wq    = (const float*)d_in[8];
  const float* Wk    = (const float*)d_in[9];
  const float* Wv    = (const float*)d_in[10];
  const float* Wfc   = (const float*)d_in[11];
  const float* catW  = (const float*)d_in[12];
  const float* catb  = (const float*)d_in[13];
  const float* outW  = (const float*)d_in[14];
  float* out = (float*)d_out;

  char* w = (char*)d_ws;
  float* Beff  = (float*)w;  w += (size_t)3 * 512 * 512 * 4;
  float* Qeff  = (float*)w;  w += (size_t)512 * 512 * 4;
  float* Veff  = (float*)w;  w += (size_t)512 * 512 * 4;
  float* kb    = (float*)w;  w += 512 * 4;
  float* qb    = (float*)w;  w += 512 * 4;
  float* h_n   = (float*)w;  w += (size_t)64 * 512 * 4;
  float* enc   = (float*)w;  w += (size_t)64 * KV_ * 512 * 4;
  u16*   Kp    = (u16*)w;    w += (size_t)64 * KV_ * 512 * 2;
  u16*   Vp    = (u16*)w;    w += (size_t)64 * KV_ * 512 * 2;
  u16*   Qp    = (u16*)w;    w += (size_t)64 * 512 * 2;
  float* h_glob = (float*)w; w += (size_t)NSET * 2 * BSET * 512 * 4;
  u32*   cnt   = (u32*)w;    w += (size_t)NSET * 1024 * CNT_STRIDE * 4;

  veff_kernel<<<1024, 256, 0, stream>>>(Wv, Veff);
  eff_mat<<<512, 512, 0, stream>>>(convw + 0, 1536, 3, Wk + 262144, nullptr, Beff);
  eff_mat<<<512, 512, 0, stream>>>(convw + 1, 1536, 3, Wk + 262144, nullptr, Beff + 262144);
  eff_mat<<<512, 512, 0, stream>>>(convw + 2, 1536, 3, Wk + 262144, Wk, Beff + 524288);
  eff_mat<<<512, 512, 0, stream>>>(convw + 2, 1536, 3, Wq + 262144, Wq, Qeff);
  eff_mat<<<1, 512, 0, stream>>>(convb, 1, 0, Wk + 262144, nullptr, kb);
  eff_mat<<<1, 512, 0, stream>>>(convb, 1, 0, Wq + 262144, nullptr, qb);

  hipMemsetAsync((void*)cnt, 0, (size_t)NSET * 1024 * CNT_STRIDE * 4, stream);
  {
    const float* a_src = src; const float* a_wih = W_ih; const float* a_whh = W_hh;
    const float* a_bih = b_ih; const float* a_bhh = b_hh;
    float* a_hg = h_glob; u32* a_cnt = cnt; float* a_enc = enc; float* a_hn = h_n;
    void* args[] = {(void*)&a_src, (void*)&a_wih, (void*)&a_whh, (void*)&a_bih,
                    (void*)&a_bhh, (void*)&a_hg, (void*)&a_cnt, (void*)&a_enc, (void*)&a_hn};
    hipError_t rc = hipLaunchCooperativeKernel(lstm_sync, dim3(256), dim3(256), args, 0, stream);
    if (rc != hipSuccess) {
      // fallback: regular launch; 256 blocks on 256 CUs are co-resident.
      lstm_sync<<<256, 256, 0, stream>>>(src, W_ih, W_hh, b_ih, b_hh,
                                         h_glob, cnt, enc, h_n);
    }
  }

  gemm_panel<<<dim3(8, KV_), 256, 0, stream>>>(enc, 64 * KV_, 3, 1, Beff, kb, Kp);
  gemm_panel<<<dim3(8, KV_), 256, 0, stream>>>(enc, 64 * KV_, 1, 0, Veff, nullptr, Vp);
  gemm_panel<<<dim3(8, 1), 256, 0, stream>>>(h_n, 64, 1, 0, Qeff, qb, Qp);
  attn_final<<<64, 256, 0, stream>>>(Qp, Kp, Vp, h_n, Wfc, catW, catb, outW, out);
}

// Round 8
// 7896.704 us; speedup vs baseline: 3.5450x; 1.6749x over previous
//
#include <hip/hip_runtime.h>
#include <hip/hip_bf16.h>

// LSTMConvATTN — round 7: kill the per-step cache-maintenance ops.
//   Round 6 confirmed the VGPR story (220 regs, FETCH 58.6GB->0.16GB) but
//   showed 12->53ms replay drift + 10x src re-fetch: agent-scope ACQUIRE
//   poll emits an L1/L2 invalidate per iteration, agent-scope RELEASE
//   arrive emits an L2 writeback per step. Both are redundant here: h and
//   cnt go through sc0/sc1 (L3 PoC) with explicit vmcnt(0) drains, and L3
//   serialization gives the ordering. This round: RELAXED atomics only.

typedef unsigned short u16;
typedef unsigned int u32;

#define KV_ 320
#define GSET 32   // WGs per set
#define NSET 8
#define BSET 8
#define CNT_STRIDE 16  // u32s per counter (64B line)

__device__ __forceinline__ u16 f2bf(float f) {
  __hip_bfloat16 h = __float2bfloat16(f);
  return __builtin_bit_cast(u16, h);
}
__device__ __forceinline__ float blo(u32 u) { return __builtin_bit_cast(float, u << 16); }
__device__ __forceinline__ float bhi(u32 u) { return __builtin_bit_cast(float, u & 0xffff0000u); }

__device__ __forceinline__ void store_f_coherent(float* p, float v) {
  asm volatile("global_store_dword %0, %1, off sc0 sc1" :: "v"(p), "v"(v) : "memory");
}

// ---------------- prep ----------------
__global__ void veff_kernel(const float* __restrict__ Wv, float* __restrict__ Veff) {
  int i = blockIdx.x * blockDim.x + threadIdx.x;
  if (i < 262144) Veff[i] = Wv[i] + Wv[262144 + i];
}

// C[i][j] = (init?init[i][j]:0) + sum_o a[o*so + i*si] * Bsrc[o*512+j]
__global__ void eff_mat(const float* __restrict__ a, int so, int si,
                        const float* __restrict__ Bsrc, const float* __restrict__ initm,
                        float* __restrict__ C) {
  int i = blockIdx.x, j = threadIdx.x;
  float acc = initm ? initm[i * 512 + j] : 0.f;
  for (int o = 0; o < 512; ++o)
    acc = fmaf(a[o * so + i * si], Bsrc[o * 512 + j], acc);
  C[i * 512 + j] = acc;
}

// ---------------- LSTM (weight-resident, synced, 256 WGs x 256 thr) --------
__global__ __launch_bounds__(256) void lstm_sync(
    const float* __restrict__ src,
    const float* __restrict__ W_ih, const float* __restrict__ W_hh,
    const float* __restrict__ b_ih, const float* __restrict__ b_hh,
    float* __restrict__ h_glob,   // [NSET][2][BSET][512]
    u32* __restrict__ cnt,        // [NSET][1024][CNT_STRIDE]
    float* __restrict__ enc_out,  // [64][KV_][512]
    float* __restrict__ h_n) {    // [64][512]
  const int tid = threadIdx.x;
  const int bid = blockIdx.x;
  const int s = bid & 7;           // set = XCD heuristic (correctness XCD-agnostic)
  const int wg = bid >> 3;         // 0..31
  const int hb = wg * 16;          // 16 hidden units per WG
  const int bg0 = s * BSET;

  const int rg = tid >> 4;         // 0..15 : row group (4 rows each)
  const int ksub = tid & 15;       // 0..15 : k sub-range (32 k's each)
  const int sw3 = ksub & 7;        // read-side XOR swizzle key

  __shared__ __align__(16) float hl[8 * 512];     // [b][k] linear (16 KB)
  __shared__ __align__(16) float xl[2][8 * 64];   // double-buffered [b][k] (4 KB)
  __shared__ __align__(16) float gb[64 * 8];      // [r_local][b] (2 KB)

  // ---- resident weights: 4 rows x 32 k = 128 floats (32 float4) ----
  float4 wreg[4][8];
  float4 wxreg[4];
#pragma unroll
  for (int rr = 0; rr < 4; ++rr) {
    const int rl = rg * 4 + rr;
    const int grow = ((rl >> 4) << 9) + hb + (rl & 15);
    const float* wrow = W_hh + (size_t)grow * 512 + (ksub << 5);
#pragma unroll
    for (int j4 = 0; j4 < 8; ++j4) {
      wreg[rr][j4] = *(const float4*)(wrow + ((j4 ^ sw3) << 2));
    }
    wxreg[rr] = *(const float4*)(W_ih + (size_t)grow * 64 + (ksub << 2));
  }

  // ---- update-thread state (tid<128: one (unit,batch) pair each) ----
  float bI = 0.f, bF = 0.f, bG = 0.f, bO = 0.f, cc = 0.f;
  const int ul = tid >> 3, bb = tid & 7;
  if (tid < 128) {
    const int r0 = hb + ul;
    bI = b_ih[r0] + b_hh[r0];
    bF = b_ih[512 + r0] + b_hh[512 + r0];
    bG = b_ih[1024 + r0] + b_hh[1024 + r0];
    bO = b_ih[1536 + r0] + b_hh[1536 + r0];
  }

  float* hg = h_glob + s * (2 * BSET * 512);
  u32* cset = cnt + (size_t)s * 1024 * CNT_STRIDE;
  const float4* hl4 = (const float4*)hl;
  const int hbase = ksub << 3;

  // initial x load (t=0): 512 floats, 2 per thread
  {
    xl[0][tid] = src[((size_t)(bg0 + (tid >> 6)) * 1024 + 0) * 64 + (tid & 63)];
    const int i2 = tid + 256;
    xl[0][i2] = src[((size_t)(bg0 + (i2 >> 6)) * 1024 + 0) * 64 + (i2 & 63)];
  }

  for (int t = 0; t < 1024; ++t) {
    // x(t+1) prefetch — issued before the poll so latency hides under the wait
    float xn0 = 0.f, xn1 = 0.f;
    if (t + 1 < 1024) {
      xn0 = src[((size_t)(bg0 + (tid >> 6)) * 1024 + (t + 1)) * 64 + (tid & 63)];
      const int i2 = tid + 256;
      xn1 = src[((size_t)(bg0 + (i2 >> 6)) * 1024 + (t + 1)) * 64 + (i2 & 63)];
    }
    // phase 1: wait for all WGs of the set to finish step t-1.
    // RELAXED poll: no per-iteration cache invalidate. Ordering comes from
    // L3 serialization: producer's sc0/sc1 h-stores are drained (vmcnt(0))
    // BEFORE its relaxed add reaches L3, and our h-loads (sc0/sc1) are
    // issued only after the poll load returns GSET.
    if (t > 0) {
      if (tid == 0) {
        while (__hip_atomic_load(&cset[(size_t)(t - 1) * CNT_STRIDE], __ATOMIC_RELAXED,
                                 __HIP_MEMORY_SCOPE_AGENT) < GSET) {
          __builtin_amdgcn_s_sleep(2);
        }
      }
      __syncthreads();  // B1 (also a compiler fence for the gather below)
    }
    // phase 2: bulk h gather (coalesced, L3-coherent): 4 float4/thread
    if (t == 0) {
      const float4 z = make_float4(0.f, 0.f, 0.f, 0.f);
      ((float4*)hl)[tid] = z;
      ((float4*)hl)[tid + 256] = z;
      ((float4*)hl)[tid + 512] = z;
      ((float4*)hl)[tid + 768] = z;
    } else {
      const float* hp = hg + (((t - 1) & 1) * (BSET * 512));
      float4 r0, r1, r2, r3;
      const float* p0 = hp + (tid << 2);
      const float* p1 = hp + ((tid + 256) << 2);
      const float* p2 = hp + ((tid + 512) << 2);
      const float* p3 = hp + ((tid + 768) << 2);
      asm volatile(
          "global_load_dwordx4 %0, %4, off sc0 sc1\n\t"
          "global_load_dwordx4 %1, %5, off sc0 sc1\n\t"
          "global_load_dwordx4 %2, %6, off sc0 sc1\n\t"
          "global_load_dwordx4 %3, %7, off sc0 sc1\n\t"
          "s_waitcnt vmcnt(0)"
          : "=&v"(r0), "=&v"(r1), "=&v"(r2), "=&v"(r3)
          : "v"(p0), "v"(p1), "v"(p2), "v"(p3)
          : "memory");
      __builtin_amdgcn_sched_barrier(0);  // keep LDS writes after the waitcnt
      ((float4*)hl)[tid] = r0;
      ((float4*)hl)[tid + 256] = r1;
      ((float4*)hl)[tid + 512] = r2;
      ((float4*)hl)[tid + 768] = r3;
    }
    __syncthreads();  // B2
    // phase 3: matvec (resident weights x LDS h), swizzled reads
    float acc[4][8];
#pragma unroll
    for (int rr = 0; rr < 4; ++rr)
#pragma unroll
      for (int b = 0; b < 8; ++b) acc[rr][b] = 0.f;
#pragma unroll
    for (int j4 = 0; j4 < 8; ++j4) {
      const int idx = hbase + (j4 ^ sw3);
      float4 hv[8];
#pragma unroll
      for (int b = 0; b < 8; ++b) hv[b] = hl4[b * 128 + idx];
#pragma unroll
      for (int rr = 0; rr < 4; ++rr) {
        const float4 w = wreg[rr][j4];
#pragma unroll
        for (int b = 0; b < 8; ++b) {
          acc[rr][b] = fmaf(w.x, hv[b].x, fmaf(w.y, hv[b].y,
                       fmaf(w.z, hv[b].z, fmaf(w.w, hv[b].w, acc[rr][b]))));
        }
      }
    }
    {
      const float4* xl4p = (const float4*)xl[t & 1];
      float4 xv[8];
#pragma unroll
      for (int b = 0; b < 8; ++b) xv[b] = xl4p[b * 16 + ksub];
#pragma unroll
      for (int rr = 0; rr < 4; ++rr) {
        const float4 w = wxreg[rr];
#pragma unroll
        for (int b = 0; b < 8; ++b) {
          acc[rr][b] = fmaf(w.x, xv[b].x, fmaf(w.y, xv[b].y,
                       fmaf(w.z, xv[b].z, fmaf(w.w, xv[b].w, acc[rr][b]))));
        }
      }
    }
    // reduce over 16 k-lanes (within-wave, width 16)
#pragma unroll
    for (int off = 1; off < 16; off <<= 1) {
#pragma unroll
      for (int rr = 0; rr < 4; ++rr) {
#pragma unroll
        for (int b = 0; b < 8; ++b)
          acc[rr][b] += __shfl_xor(acc[rr][b], off, 16);
      }
    }
    if (ksub == 0) {
#pragma unroll
      for (int rr = 0; rr < 4; ++rr) {
        const int rl = rg * 4 + rr;
        ((float4*)gb)[rl * 2 + 0] = make_float4(acc[rr][0], acc[rr][1], acc[rr][2], acc[rr][3]);
        ((float4*)gb)[rl * 2 + 1] = make_float4(acc[rr][4], acc[rr][5], acc[rr][6], acc[rr][7]);
      }
    }
    __syncthreads();  // B3
    // phase 4a: stash prefetched x
    if (t + 1 < 1024) {
      xl[(t + 1) & 1][tid] = xn0;
      xl[(t + 1) & 1][tid + 256] = xn1;
    }
    // phase 4b: gate update + h publication (gb[rl][b], rl = gate*16 + unit)
    if (tid < 128) {
      const float gi = gb[(ul) * 8 + bb] + bI;
      const float gf = gb[(16 + ul) * 8 + bb] + bF;
      const float gg = gb[(32 + ul) * 8 + bb] + bG;
      const float go = gb[(48 + ul) * 8 + bb] + bO;
      const float iv = 1.f / (1.f + expf(-gi));
      const float fv = 1.f / (1.f + expf(-gf));
      const float gv = tanhf(gg);
      const float ov = 1.f / (1.f + expf(-go));
      cc = fv * cc + iv * gv;
      const float hv = ov * tanhf(cc);
      store_f_coherent(&hg[(t & 1) * (BSET * 512) + (bb << 9) + hb + ul], hv);
      if (t < KV_) enc_out[((size_t)(bg0 + bb) * KV_ + t) * 512 + hb + ul] = hv;
      if (t == 1023) h_n[(size_t)(bg0 + bb) * 512 + hb + ul] = hv;
    }
    asm volatile("s_waitcnt vmcnt(0)" ::: "memory");  // drain h stores to L3
    __syncthreads();  // B4
    // phase 5: arrive (RELAXED — h stores already at L3 per the drain above)
    if (t < 1023 && tid == 0) {
      __hip_atomic_fetch_add(&cset[(size_t)t * CNT_STRIDE], 1u, __ATOMIC_RELAXED,
                             __HIP_MEMORY_SCOPE_AGENT);
    }
  }
}

// ---------------- panel GEMM (fp32 in, bf16 out) ----------------
__global__ __launch_bounds__(256) void gemm_panel(
    const float* __restrict__ A, int M, int nseg, int shifted,
    const float* __restrict__ Bm, const float* __restrict__ bias,
    u16* __restrict__ C) {
  __shared__ float As[16][72];
  __shared__ float Bs[16][64];
  const int tid = threadIdx.x;
  const int nx = blockIdx.x, my = blockIdx.y;
  const int tx = tid & 15, ty = tid >> 4;
  const int m0 = ty * 4, n0 = tx * 4;
  const int lr = tid >> 2, lc = (tid & 3) * 4;
  const int kr = tid >> 4, nc = (tid & 15) * 4;
  float acc[4][4] = {};
  const int KK = nseg * 512;
  const int rA = my * 64 + lr;
  const int tloc = rA % KV_;
  for (int kk = 0; kk < KK; kk += 16) {
    const int seg = kk >> 9, k0 = kk & 511;
    float4 av = make_float4(0.f, 0.f, 0.f, 0.f);
    if (rA < M) {
      int arow = rA, valid = 1;
      if (shifted) { arow = rA + seg - 2; valid = (tloc + seg - 2) >= 0; }
      if (valid) av = *(const float4*)&A[(size_t)arow * 512 + k0 + lc];
    }
    As[lc + 0][lr] = av.x; As[lc + 1][lr] = av.y;
    As[lc + 2][lr] = av.z; As[lc + 3][lr] = av.w;
    *(float4*)&Bs[kr][nc] = *(const float4*)&Bm[(size_t)(kk + kr) * 512 + nx * 64 + nc];
    __syncthreads();
#pragma unroll
    for (int k = 0; k < 16; ++k) {
      float4 A4 = *(const float4*)&As[k][m0];
      float4 B4 = *(const float4*)&Bs[k][n0];
      float ar[4] = {A4.x, A4.y, A4.z, A4.w};
      float br[4] = {B4.x, B4.y, B4.z, B4.w};
#pragma unroll
      for (int ii = 0; ii < 4; ++ii)
#pragma unroll
        for (int jj = 0; jj < 4; ++jj)
          acc[ii][jj] = fmaf(ar[ii], br[jj], acc[ii][jj]);
    }
    __syncthreads();
  }
#pragma unroll
  for (int ii = 0; ii < 4; ++ii) {
    int r = my * 64 + m0 + ii;
    if (r < M) {
#pragma unroll
      for (int jj = 0; jj < 4; ++jj) {
        int col = nx * 64 + n0 + jj;
        float v = acc[ii][jj] + (bias ? bias[col] : 0.f);
        C[(size_t)r * 512 + col] = f2bf(v);
      }
    }
  }
}

// ---------------- attention + head ----------------
__global__ __launch_bounds__(256) void attn_final(
    const u16* __restrict__ Qp, const u16* __restrict__ Kp, const u16* __restrict__ Vp,
    const float* __restrict__ h_n, const float* __restrict__ Wfc,
    const float* __restrict__ catW, const float* __restrict__ catb,
    const float* __restrict__ outW, float* __restrict__ out) {
  const int b = blockIdx.x, tid = threadIdx.x;
  __shared__ float sc[8 * KV_];
  __shared__ float ctx[512];
  __shared__ float av[512];
  __shared__ float ha[64];
  __shared__ uint4 qs[64];
  if (tid < 64) qs[tid] = ((const uint4*)(Qp + (size_t)b * 512))[tid];
  __syncthreads();
  for (int idx = tid; idx < 8 * KV_; idx += 256) {
    int h = idx / KV_, t = idx % KV_;
    const uint4* kr4 = (const uint4*)(Kp + ((size_t)(b * KV_ + t)) * 512 + h * 64);
    float s = 0.f;
#pragma unroll
    for (int u = 0; u < 8; ++u) {
      uint4 kv = kr4[u]; uint4 qv = qs[h * 8 + u];
      s += blo(kv.x) * blo(qv.x) + bhi(kv.x) * bhi(qv.x)
         + blo(kv.y) * blo(qv.y) + bhi(kv.y) * bhi(qv.y)
         + blo(kv.z) * blo(qv.z) + bhi(kv.z) * bhi(qv.z)
         + blo(kv.w) * blo(qv.w) + bhi(kv.w) * bhi(qv.w);
    }
    sc[h * KV_ + t] = s * 0.125f;
  }
  __syncthreads();
  {
    int h = tid >> 5, l = tid & 31;
    float m = -1e30f;
    for (int t = l; t < KV_; t += 32) m = fmaxf(m, sc[h * KV_ + t]);
    for (int o = 16; o; o >>= 1) m = fmaxf(m, __shfl_xor(m, o, 32));
    float sum = 0.f;
    for (int t = l; t < KV_; t += 32) { float e = expf(sc[h * KV_ + t] - m); sc[h * KV_ + t] = e; sum += e; }
    for (int o = 16; o; o >>= 1) sum += __shfl_xor(sum, o, 32);
    float inv = 1.f / sum;
    for (int t = l; t < KV_; t += 32) sc[h * KV_ + t] *= inv;
  }
  __syncthreads();
  for (int j = tid; j < 512; j += 256) {
    int h = j >> 6, d = j & 63;
    const u16* vp = Vp + (size_t)(b * KV_) * 512 + h * 64 + d;
    float a = 0.f;
    for (int t = 0; t < KV_; ++t)
      a = fmaf(sc[h * KV_ + t], blo((u32)vp[(size_t)t * 512]), a);
    ctx[j] = a;
  }
  __syncthreads();
  for (int j = tid; j < 512; j += 256) {
    float a = 0.f;
    for (int i = 0; i < 512; ++i) a = fmaf(ctx[i], Wfc[(size_t)i * 512 + j], a);
    av[j] = a;
  }
  __syncthreads();
  if (tid < 64) {
    float a = catb[tid];
    const float* hb = h_n + (size_t)b * 512;
    for (int i = 0; i < 512; ++i) a = fmaf(hb[i], catW[i * 64 + tid], a);
    for (int i = 0; i < 512; ++i) a = fmaf(av[i], catW[(512 + i) * 64 + tid], a);
    ha[tid] = a;
  }
  __syncthreads();
  if (tid < 64) {
    float v = ha[tid] * outW[tid];
    for (int o = 32; o; o >>= 1) v += __shfl_xor(v, o, 64);
    if (tid == 0) out[b] = v;
  }
}

extern "C" void kernel_launch(void* const* d_in, const int* in_sizes, int n_in,
                              void* d_out, int out_size, void* d_ws, size_t ws_size,
                              hipStream_t stream) {
  const float* src   = (const float*)d_in[0];
  const float* W_ih  = (const float*)d_in[2];
  const float* W_hh  = (const float*)d_in[3];
  const float* b_ih  = (const float*)d_in[4];
  const float* b_hh  = (const float*)d_in[5];
  const float* convw = (const float*)d_in[6];
  const float* convb = (const float*)d_in[7];
  const float* Wq    = (const float*)d_in[8];
  const float* Wk    = (const float*)d_in[9];
  const float* Wv    = (const float*)d_in[10];
  const float* Wfc   = (const float*)d_in[11];
  const float* catW  = (const float*)d_in[12];
  const float* catb  = (const float*)d_in[13];
  const float* outW  = (const float*)d_in[14];
  float* out = (float*)d_out;

  char* w = (char*)d_ws;
  float* Beff  = (float*)w;  w += (size_t)3 * 512 * 512 * 4;
  float* Qeff  = (float*)w;  w += (size_t)512 * 512 * 4;
  float* Veff  = (float*)w;  w += (size_t)512 * 512 * 4;
  float* kb    = (float*)w;  w += 512 * 4;
  float* qb    = (float*)w;  w += 512 * 4;
  float* h_n   = (float*)w;  w += (size_t)64 * 512 * 4;
  float* enc   = (float*)w;  w += (size_t)64 * KV_ * 512 * 4;
  u16*   Kp    = (u16*)w;    w += (size_t)64 * KV_ * 512 * 2;
  u16*   Vp    = (u16*)w;    w += (size_t)64 * KV_ * 512 * 2;
  u16*   Qp    = (u16*)w;    w += (size_t)64 * 512 * 2;
  float* h_glob = (float*)w; w += (size_t)NSET * 2 * BSET * 512 * 4;
  u32*   cnt   = (u32*)w;    w += (size_t)NSET * 1024 * CNT_STRIDE * 4;

  veff_kernel<<<1024, 256, 0, stream>>>(Wv, Veff);
  eff_mat<<<512, 512, 0, stream>>>(convw + 0, 1536, 3, Wk + 262144, nullptr, Beff);
  eff_mat<<<512, 512, 0, stream>>>(convw + 1, 1536, 3, Wk + 262144, nullptr, Beff + 262144);
  eff_mat<<<512, 512, 0, stream>>>(convw + 2, 1536, 3, Wk + 262144, Wk, Beff + 524288);
  eff_mat<<<512, 512, 0, stream>>>(convw + 2, 1536, 3, Wq + 262144, Wq, Qeff);
  eff_mat<<<1, 512, 0, stream>>>(convb, 1, 0, Wk + 262144, nullptr, kb);
  eff_mat<<<1, 512, 0, stream>>>(convb, 1, 0, Wq + 262144, nullptr, qb);

  hipMemsetAsync((void*)cnt, 0, (size_t)NSET * 1024 * CNT_STRIDE * 4, stream);
  {
    const float* a_src = src; const float* a_wih = W_ih; const float* a_whh = W_hh;
    const float* a_bih = b_ih; const float* a_bhh = b_hh;
    float* a_hg = h_glob; u32* a_cnt = cnt; float* a_enc = enc; float* a_hn = h_n;
    void* args[] = {(void*)&a_src, (void*)&a_wih, (void*)&a_whh, (void*)&a_bih,
                    (void*)&a_bhh, (void*)&a_hg, (void*)&a_cnt, (void*)&a_enc, (void*)&a_hn};
    hipError_t rc = hipLaunchCooperativeKernel(lstm_sync, dim3(256), dim3(256), args, 0, stream);
    if (rc != hipSuccess) {
      // fallback: regular launch; 256 blocks on 256 CUs are co-resident.
      lstm_sync<<<256, 256, 0, stream>>>(src, W_ih, W_hh, b_ih, b_hh,
                                         h_glob, cnt, enc, h_n);
    }
  }

  gemm_panel<<<dim3(8, KV_), 256, 0, stream>>>(enc, 64 * KV_, 3, 1, Beff, kb, Kp);
  gemm_panel<<<dim3(8, KV_), 256, 0, stream>>>(enc, 64 * KV_, 1, 0, Veff, nullptr, Vp);
  gemm_panel<<<dim3(8, 1), 256, 0, stream>>>(h_n, 64, 1, 0, Qeff, qb, Qp);
  attn_final<<<64, 256, 0, stream>>>(Qp, Kp, Vp, h_n, Wfc, catW, catb, outW, out);
}